// Round 1
// baseline (411.822 us; speedup 1.0000x reference)
//
#include <hip/hip_runtime.h>
#include <math.h>

#define DF 768      // feature dim
#define NN 64       // nodes
#define DN 832      // batch row stride (D + N)
#define LDH 776     // h row-major LDS row stride (halves)
#define LDT 72      // hpT / attn LDS row stride (halves)
#define LDA 1540    // final_mlp A-tile row stride (halves): 770 dwords % 32 == 2 -> ~2-way (free)
#define NEG_SLOPE 0.2f

typedef _Float16 f16;
typedef __attribute__((ext_vector_type(4))) _Float16 f16x4;
typedef __attribute__((ext_vector_type(8))) _Float16 f16x8;
typedef __attribute__((ext_vector_type(4))) float f32x4;

__device__ __forceinline__ float tanh_fast(float x) {
  return 1.0f - 2.0f / (__expf(2.0f * x) + 1.0f);
}

// ---------- prep: transpose w (768x768 fp32) -> wT[o][k] f16 ----------
__global__ void prep_wT(const float* __restrict__ w, f16* __restrict__ wT) {
  __shared__ float tile[32][33];
  int bx = blockIdx.x % 24;   // o tile
  int by = blockIdx.x / 24;   // k tile
  int tx = threadIdx.x & 31;
  int ty = threadIdx.x >> 5;  // 0..7
#pragma unroll
  for (int rr = 0; rr < 4; ++rr)
    tile[ty + rr * 8][tx] = w[(size_t)(by * 32 + ty + rr * 8) * DF + bx * 32 + tx];
  __syncthreads();
#pragma unroll
  for (int rr = 0; rr < 4; ++rr)
    wT[(size_t)(bx * 32 + ty + rr * 8) * DF + by * 32 + tx] = (f16)tile[tx][ty + rr * 8];
}

// ---------- prep: mlp_w fp32 -> f16 ----------
__global__ void prep_mlp(const float* __restrict__ mw, f16* __restrict__ mwh) {
  int i = blockIdx.x * 256 + threadIdx.x;
  mwh[i] = (f16)mw[i];
}

// ---------- fused 2-layer GAT: one workgroup (1024 thr, 16 waves) per batch item ----------
// R6 theory: GEMM1 per-iter = L2 wT stream (~860cy) + LDS A-frags (~770cy) +
// MFMA (~240cy) SERIALIZED (~2000cy observed) because 1-deep prefetch +
// barrier phase-lock leave the wT L2 latency exposed. Fix: 2-deep B pipeline
// via manual 3-buffer rotation (8 macro-iters x 3 k-steps, no rotation movs).
// Register-neutral: af[4] (16 VGPR) -> transient per-rt (4), +12 for 3rd B buf.
// B preloads issued BEFORE the layer-entry barrier (no LDS dep) so their
// latency hides under the barrier drain. Tripwire: WRITE_SIZE balloon = spill.
__global__ __launch_bounds__(1024, 4) void gat_fused(
    const float* __restrict__ batch,
    const f16* __restrict__ wT,          // (768 x 768), wT[o][k] = w[k][o]
    const float* __restrict__ a_src,
    const float* __restrict__ a_dst,
    const float* __restrict__ gat_bias,
    f16* __restrict__ cneighW)           // (512 x 768) l2normed h[:,0]
{
  // Hbuf doubles as: h row-major (64 x LDH) and hpT (768 x LDT)
  __shared__ __align__(16) f16 Hbuf[DF * LDT];   // 110592 B
  __shared__ __align__(16) f16 attnB[NN * LDT];  // 9216 B
  __shared__ float asrcL[DF], adstL[DF], biasL[DF];
  __shared__ float srcv[NN], dstv[NN];
  __shared__ float redS[16 * NN], redD[16 * NN];
  __shared__ unsigned long long maskRow[NN];
  __shared__ float attn0[NN];
  __shared__ float h2row[DF];
  __shared__ float ssqred[16];

  const int tid  = threadIdx.x;
  const int lane = tid & 63;
  const int wv   = tid >> 6;     // wave 0..15
  const int l16  = lane & 15;
  const int quad = lane >> 4;    // 0..3
  const int b    = blockIdx.x;
  const int cb   = wv * 48;      // this wave's column base (16 waves x 48 = 768)

  const float* bb = batch + (size_t)b * (NN * DN);

  // params -> LDS
  for (int i = tid; i < DF; i += 1024) {
    asrcL[i] = a_src[i];
    adstL[i] = a_dst[i];
    biasL[i] = gat_bias[i];
  }
  // stage h0 = features (fp32 -> f16), row-major, float4-vectorized
  for (int i = tid; i < NN * (DF / 4); i += 1024) {
    int r = i / (DF / 4), c4 = i - r * (DF / 4);
    float4 v = *(const float4*)&bb[r * DN + c4 * 4];
    f16x4 h4 = {(f16)v.x, (f16)v.y, (f16)v.z, (f16)v.w};
    *(f16x4*)&Hbuf[r * LDH + c4 * 4] = h4;
  }
  // adjacency mask via ballot: wave wv builds rows 4*wv..4*wv+3
#pragma unroll
  for (int r = 0; r < 4; ++r) {
    int n = wv * 4 + r;
    float av = bb[n * DN + DF + lane];
    unsigned long long m = __ballot(av != 0.0f);
    if (lane == 0) maskRow[n] = m | (1ULL << n);   // eye
  }
  // NOTE: no barrier here — the layer-entry barrier below covers these writes,
  // and the layer-0 B preload overlaps the barrier drain.

  // per-wave wT base: columns cb+ct*16+l16, k offset quad*8
  const f16* wp = wT + (size_t)(cb + l16) * DF + quad * 8;

  for (int layer = 0; layer < 2; ++layer) {
    // ================= GEMM1: hp = h @ w =================
    f32x4 acc[4][3];
#pragma unroll
    for (int rt = 0; rt < 4; ++rt)
#pragma unroll
      for (int ct = 0; ct < 3; ++ct)
        acc[rt][ct] = (f32x4){0.f, 0.f, 0.f, 0.f};

    // 3-buffer rotation, 2 k-steps of prefetch depth.
    // Ba used at k0+96j, Bb at k0+32+96j, Bc at k0+64+96j.
    f16x8 Ba[3], Bb[3], Bc[3];
#pragma unroll
    for (int ct = 0; ct < 3; ++ct) {
      Ba[ct] = *(const f16x8*)(wp + (size_t)(ct * 16) * DF);
      Bb[ct] = *(const f16x8*)(wp + (size_t)(ct * 16) * DF + 32);
    }
    __syncthreads();   // Hbuf (h) + params/mask ready; preloads fly under drain

#pragma clang loop unroll(disable)
    for (int k0 = 0; k0 < DF; k0 += 96) {
      // ---- step 0: compute k0 with Ba, prefetch k0+64 -> Bc (used 2 steps on)
      {
        int kp = k0 + 64;   // max 736 < DF, never wraps
#pragma unroll
        for (int ct = 0; ct < 3; ++ct)
          Bc[ct] = *(const f16x8*)(wp + (size_t)(ct * 16) * DF + kp);
#pragma unroll
        for (int rt = 0; rt < 4; ++rt) {
          f16x8 a = *(const f16x8*)&Hbuf[(rt * 16 + l16) * LDH + k0 + quad * 8];
#pragma unroll
          for (int ct = 0; ct < 3; ++ct)
            acc[rt][ct] = __builtin_amdgcn_mfma_f32_16x16x32_f16(a, Ba[ct], acc[rt][ct], 0, 0, 0);
        }
      }
      // ---- step 1: compute k0+32 with Bb, prefetch k0+96 -> Ba
      {
        int kp = k0 + 96; kp = (kp < DF) ? kp : 0;   // wrap: harmless reload
#pragma unroll
        for (int ct = 0; ct < 3; ++ct)
          Ba[ct] = *(const f16x8*)(wp + (size_t)(ct * 16) * DF + kp);
#pragma unroll
        for (int rt = 0; rt < 4; ++rt) {
          f16x8 a = *(const f16x8*)&Hbuf[(rt * 16 + l16) * LDH + k0 + 32 + quad * 8];
#pragma unroll
          for (int ct = 0; ct < 3; ++ct)
            acc[rt][ct] = __builtin_amdgcn_mfma_f32_16x16x32_f16(a, Bb[ct], acc[rt][ct], 0, 0, 0);
        }
      }
      // ---- step 2: compute k0+64 with Bc, prefetch k0+128 -> Bb
      {
        int kp = k0 + 128; kp = (kp < DF) ? kp : 32;  // wrap: harmless reload
#pragma unroll
        for (int ct = 0; ct < 3; ++ct)
          Bb[ct] = *(const f16x8*)(wp + (size_t)(ct * 16) * DF + kp);
#pragma unroll
        for (int rt = 0; rt < 4; ++rt) {
          f16x8 a = *(const f16x8*)&Hbuf[(rt * 16 + l16) * LDH + k0 + 64 + quad * 8];
#pragma unroll
          for (int ct = 0; ct < 3; ++ct)
            acc[rt][ct] = __builtin_amdgcn_mfma_f32_16x16x32_f16(a, Bc[ct], acc[rt][ct], 0, 0, 0);
        }
      }
    }
    __syncthreads();   // all h reads done

    // write hp transposed: hpT[o][m]; C layout row=rt*16+quad*4+i, col=cb+ct*16+l16
#pragma unroll
    for (int rt = 0; rt < 4; ++rt)
#pragma unroll
      for (int ct = 0; ct < 3; ++ct) {
        int row0 = rt * 16 + quad * 4;
        int col  = cb + ct * 16 + l16;
        f16x4 h4 = {(f16)acc[rt][ct][0], (f16)acc[rt][ct][1],
                    (f16)acc[rt][ct][2], (f16)acc[rt][ct][3]};
        *(f16x4*)&Hbuf[col * LDT + row0] = h4;
      }
    __syncthreads();

    // ================= src/dst: th = tanh(hp), dot with a_src/a_dst =================
    {
      float s = 0.f, d = 0.f;
      int m = lane;
      int o0 = wv * 48;
      for (int o = o0; o < o0 + 48; ++o) {
        float t = tanh_fast((float)Hbuf[o * LDT + m]);
        s += t * asrcL[o];
        d += t * adstL[o];
      }
      redS[wv * 64 + m] = s;
      redD[wv * 64 + m] = d;
    }
    __syncthreads();
    if (tid < 64) {
      float s = 0.f, d = 0.f;
#pragma unroll
      for (int q = 0; q < 16; ++q) { s += redS[q * 64 + tid]; d += redD[q * 64 + tid]; }
      srcv[tid] = s;
      dstv[tid] = d;
    }
    __syncthreads();

    if (layer == 0) {
      // ---- full attention: wave wv does rows 4*wv..4*wv+3, lane = neighbor m ----
#pragma unroll
      for (int r = 0; r < 4; ++r) {
        int n = wv * 4 + r;
        float logit = srcv[n] + dstv[lane];
        logit = logit >= 0.f ? logit : NEG_SLOPE * logit;
        bool ok = (maskRow[n] >> lane) & 1ULL;
        float v = ok ? logit : -1e30f;
        float mx = v;
#pragma unroll
        for (int off = 32; off > 0; off >>= 1) mx = fmaxf(mx, __shfl_xor(mx, off, 64));
        float e = ok ? __expf(v - mx) : 0.f;
        float sm = e;
#pragma unroll
        for (int off = 32; off > 0; off >>= 1) sm += __shfl_xor(sm, off, 64);
        attnB[n * LDT + lane] = (f16)(e / sm);
      }
      __syncthreads();

      // ---- GEMM2: h_new = attn @ hp  (A=attnB row-major, B=hpT) ----
      f32x4 acc2[4][3];
#pragma unroll
      for (int rt = 0; rt < 4; ++rt)
#pragma unroll
        for (int ct = 0; ct < 3; ++ct)
          acc2[rt][ct] = (f32x4){0.f, 0.f, 0.f, 0.f};
#pragma unroll
      for (int k0 = 0; k0 < NN; k0 += 32) {
        f16x8 af2[4];
#pragma unroll
        for (int rt = 0; rt < 4; ++rt)
          af2[rt] = *(const f16x8*)&attnB[(rt * 16 + l16) * LDT + k0 + quad * 8];
#pragma unroll
        for (int ct = 0; ct < 3; ++ct) {
          f16x8 bf = *(const f16x8*)&Hbuf[(cb + ct * 16 + l16) * LDT + k0 + quad * 8];
#pragma unroll
          for (int rt = 0; rt < 4; ++rt)
            acc2[rt][ct] = __builtin_amdgcn_mfma_f32_16x16x32_f16(af2[rt], bf, acc2[rt][ct], 0, 0, 0);
        }
      }
      __syncthreads();  // all hpT reads done before overwriting Hbuf
      // h_new (+bias) -> Hbuf row-major (next layer's h)
#pragma unroll
      for (int rt = 0; rt < 4; ++rt)
#pragma unroll
        for (int ct = 0; ct < 3; ++ct)
#pragma unroll
          for (int i = 0; i < 4; ++i) {
            int row = rt * 16 + quad * 4 + i;
            int col = cb + ct * 16 + l16;
            Hbuf[row * LDH + col] = (f16)(acc2[rt][ct][i] + biasL[col]);
          }
      // NOTE: no barrier here — layer-1 entry barrier (after its B preload)
      // covers these writes, overlapping the preload with the drain.
    } else {
      // ---- layer 2: only row 0 of h_new is ever used ----
      if (wv == 0) {
        float logit = srcv[0] + dstv[lane];
        logit = logit >= 0.f ? logit : NEG_SLOPE * logit;
        bool ok = (maskRow[0] >> lane) & 1ULL;
        float v = ok ? logit : -1e30f;
        float mx = v;
#pragma unroll
        for (int off = 32; off > 0; off >>= 1) mx = fmaxf(mx, __shfl_xor(mx, off, 64));
        float e = ok ? __expf(v - mx) : 0.f;
        float sm = e;
#pragma unroll
        for (int off = 32; off > 0; off >>= 1) sm += __shfl_xor(sm, off, 64);
        attn0[lane] = e / sm;   // keep fp32
      }
      __syncthreads();
      // h2_0[o] = bias[o] + sum_m attn0[m] * hpT[o][m]  (row o is 64 contiguous halves)
      if (tid < DF) {
        const int o = tid;
        const f16* rowp = &Hbuf[o * LDT];
        float a = biasL[o];
#pragma unroll
        for (int j = 0; j < 8; ++j) {
          f16x8 v = *(const f16x8*)&rowp[j * 8];
#pragma unroll
          for (int e = 0; e < 8; ++e) a += attn0[j * 8 + e] * (float)v[e];
        }
        h2row[o] = a;
      }
      __syncthreads();
      // l2norm of h2_0 -> cneighW
      float p = (tid < DF) ? h2row[tid] * h2row[tid] : 0.f;
#pragma unroll
      for (int off = 32; off > 0; off >>= 1) p += __shfl_xor(p, off, 64);
      if (lane == 0) ssqred[wv] = p;
      __syncthreads();
      if (tid == 0) {
        float ss = 0.f;
#pragma unroll
        for (int q = 0; q < 16; ++q) ss += ssqred[q];
        ssqred[0] = 1.0f / fmaxf(sqrtf(ss), 1e-12f);
      }
      __syncthreads();
      float scale = ssqred[0];
      if (tid < DF)
        cneighW[(size_t)b * DF + tid] = (f16)(h2row[tid] * scale);
    }
  }
}

// ---------- final MLP GEMM: grid (32 M-tiles, 6 N-chunks), 256 thr ----------
// R6: 3-buffer 2-deep B pipeline (1 wave/SIMD here -> fully latency-exposed
// before); B preload hoisted above the A-stage barrier.
__global__ __launch_bounds__(256) void final_mlp(
    const float* __restrict__ batch,
    const f16* __restrict__ cneighW,
    const f16* __restrict__ mwh,         // (768 x 1536) row-major (d, j)
    const float* __restrict__ mlp_b,
    float* __restrict__ out)
{
  __shared__ __align__(16) f16 Abuf[16 * LDA];   // 49280 B
  const int tid  = threadIdx.x;
  const int lane = tid & 63;
  const int wv   = tid >> 6;          // 0..3
  const int l16  = lane & 15;
  const int quad = lane >> 4;
  const int b0   = blockIdx.x * 16;   // batch-row tile
  const int cb   = blockIdx.y * 128 + wv * 32;  // column base (2 ct of 16)

  const f16* mp = mwh + (size_t)(cb + l16) * (2 * DF) + quad * 8;
  // B preload (no LDS dep) — overlaps the A-stage + barrier
  f16x8 Ba[2], Bb[2], Bc[2];
  Ba[0] = *(const f16x8*)(mp);
  Ba[1] = *(const f16x8*)(mp + (size_t)16 * (2 * DF));
  Bb[0] = *(const f16x8*)(mp + 32);
  Bb[1] = *(const f16x8*)(mp + (size_t)16 * (2 * DF) + 32);

  // stage A: 16 rows x 1536 halves; j<768 from batch node-0 (fp32), else cneigh (f16)
  for (int i = tid; i < 16 * 384; i += 256) {
    int r = i / 384, c4 = i - r * 384;
    int j = c4 * 4;
    f16x4 h4;
    if (j < DF) {
      float4 v = *(const float4*)&batch[(size_t)(b0 + r) * (NN * DN) + j];
      h4 = (f16x4){(f16)v.x, (f16)v.y, (f16)v.z, (f16)v.w};
    } else {
      h4 = *(const f16x4*)&cneighW[(size_t)(b0 + r) * DF + (j - DF)];
    }
    *(f16x4*)&Abuf[r * LDA + j] = h4;
  }
  __syncthreads();

  f32x4 acc[2];
  acc[0] = (f32x4){0.f, 0.f, 0.f, 0.f};
  acc[1] = (f32x4){0.f, 0.f, 0.f, 0.f};

#pragma clang loop unroll(disable)
  for (int k0 = 0; k0 < 2 * DF; k0 += 96) {
    // step 0: compute k0 with Ba, prefetch k0+64 -> Bc
    {
      int kp = k0 + 64;   // max 1504 < 1536, never wraps
      Bc[0] = *(const f16x8*)(mp + kp);
      Bc[1] = *(const f16x8*)(mp + (size_t)16 * (2 * DF) + kp);
      f16x4 a0 = *(const f16x4*)&Abuf[l16 * LDA + k0 + quad * 8];
      f16x4 a1 = *(const f16x4*)&Abuf[l16 * LDA + k0 + quad * 8 + 4];
      f16x8 af = {a0[0], a0[1], a0[2], a0[3], a1[0], a1[1], a1[2], a1[3]};
      acc[0] = __builtin_amdgcn_mfma_f32_16x16x32_f16(af, Ba[0], acc[0], 0, 0, 0);
      acc[1] = __builtin_amdgcn_mfma_f32_16x16x32_f16(af, Ba[1], acc[1], 0, 0, 0);
    }
    // step 1: compute k0+32 with Bb, prefetch k0+96 -> Ba
    {
      int kp = k0 + 96; kp = (kp < 2 * DF) ? kp : 0;
      Ba[0] = *(const f16x8*)(mp + kp);
      Ba[1] = *(const f16x8*)(mp + (size_t)16 * (2 * DF) + kp);
      f16x4 a0 = *(const f16x4*)&Abuf[l16 * LDA + k0 + 32 + quad * 8];
      f16x4 a1 = *(const f16x4*)&Abuf[l16 * LDA + k0 + 32 + quad * 8 + 4];
      f16x8 af = {a0[0], a0[1], a0[2], a0[3], a1[0], a1[1], a1[2], a1[3]};
      acc[0] = __builtin_amdgcn_mfma_f32_16x16x32_f16(af, Bb[0], acc[0], 0, 0, 0);
      acc[1] = __builtin_amdgcn_mfma_f32_16x16x32_f16(af, Bb[1], acc[1], 0, 0, 0);
    }
    // step 2: compute k0+64 with Bc, prefetch k0+128 -> Bb
    {
      int kp = k0 + 128; kp = (kp < 2 * DF) ? kp : 32;
      Bb[0] = *(const f16x8*)(mp + kp);
      Bb[1] = *(const f16x8*)(mp + (size_t)16 * (2 * DF) + kp);
      f16x4 a0 = *(const f16x4*)&Abuf[l16 * LDA + k0 + 64 + quad * 8];
      f16x4 a1 = *(const f16x4*)&Abuf[l16 * LDA + k0 + 64 + quad * 8 + 4];
      f16x8 af = {a0[0], a0[1], a0[2], a0[3], a1[0], a1[1], a1[2], a1[3]};
      acc[0] = __builtin_amdgcn_mfma_f32_16x16x32_f16(af, Bc[0], acc[0], 0, 0, 0);
      acc[1] = __builtin_amdgcn_mfma_f32_16x16x32_f16(af, Bc[1], acc[1], 0, 0, 0);
    }
  }

  // epilogue: + bias, store raw (l2norm_rows normalizes)
#pragma unroll
  for (int ct = 0; ct < 2; ++ct) {
    int col = cb + ct * 16 + l16;
    float bv = mlp_b[col];
#pragma unroll
    for (int i = 0; i < 4; ++i) {
      int row = quad * 4 + i;
      out[(size_t)(b0 + row) * DF + col] = acc[ct][i] + bv;
    }
  }
}

// ---------- per-row l2 normalization of out (512 x 768 fp32) ----------
__global__ __launch_bounds__(256) void l2norm_rows(float* __restrict__ out) {
  const int lane = threadIdx.x & 63;
  const int wv   = threadIdx.x >> 6;
  const int row  = blockIdx.x * 4 + wv;
  float* rp = out + (size_t)row * DF;
  float v[12];
  float ss = 0.f;
#pragma unroll
  for (int j = 0; j < 12; ++j) {
    v[j] = rp[j * 64 + lane];
    ss += v[j] * v[j];
  }
#pragma unroll
  for (int off = 32; off > 0; off >>= 1) ss += __shfl_xor(ss, off, 64);
  float sc = 1.0f / fmaxf(sqrtf(ss), 1e-12f);
#pragma unroll
  for (int j = 0; j < 12; ++j) rp[j * 64 + lane] = v[j] * sc;
}

extern "C" void kernel_launch(void* const* d_in, const int* in_sizes, int n_in,
                              void* d_out, int out_size, void* d_ws, size_t ws_size,
                              hipStream_t stream) {
  const float* batch    = (const float*)d_in[0];  // (512, 64, 832)
  const float* w        = (const float*)d_in[1];  // (1, 768, 768)
  const float* a_src    = (const float*)d_in[2];  // (1, 768, 1)
  const float* a_dst    = (const float*)d_in[3];  // (1, 768, 1)
  const float* gat_bias = (const float*)d_in[4];  // (768,)
  const float* mlp_w    = (const float*)d_in[5];  // (768, 1536)
  const float* mlp_b    = (const float*)d_in[6];  // (768,)
  float* out = (float*)d_out;

  // workspace layout (f16): wT 768x768 | mlp_w 768x1536 | cneigh 512x768
  f16* wT      = (f16*)d_ws;
  f16* mwh     = wT + (size_t)DF * DF;
  f16* cneighW = mwh + (size_t)DF * 2 * DF;

  prep_wT<<<dim3(24 * 24), dim3(256), 0, stream>>>(w, wT);
  prep_mlp<<<dim3((DF * 2 * DF) / 256), dim3(256), 0, stream>>>(mlp_w, mwh);
  gat_fused<<<dim3(512), dim3(1024), 0, stream>>>(batch, wT, a_src, a_dst, gat_bias, cneighW);
  final_mlp<<<dim3(32, 6), dim3(256), 0, stream>>>(batch, cneighW, mwh, mlp_b, out);
  l2norm_rows<<<dim3(128), dim3(256), 0, stream>>>(out);
}

// Round 2
// 383.939 us; speedup vs baseline: 1.0726x; 1.0726x over previous
//
#include <hip/hip_runtime.h>
#include <math.h>

#define DF 768      // feature dim
#define NN 64       // nodes
#define DN 832      // batch row stride (D + N)
#define LDH 776     // h row-major LDS row stride (halves)
#define LDT 72      // hpT / attn LDS row stride (halves)
#define LDA 1540    // final_mlp A-tile row stride (halves)
#define NEG_SLOPE 0.2f

typedef _Float16 f16;
typedef __attribute__((ext_vector_type(4))) _Float16 f16x4;
typedef __attribute__((ext_vector_type(8))) _Float16 f16x8;
typedef __attribute__((ext_vector_type(4))) float f32x4;

__device__ __forceinline__ float tanh_fast(float x) {
  return 1.0f - 2.0f / (__expf(2.0f * x) + 1.0f);
}

// ---------- prep: transpose w (768x768 fp32) -> wT[o][k] f16 ----------
__global__ void prep_wT(const float* __restrict__ w, f16* __restrict__ wT) {
  __shared__ float tile[32][33];
  int bx = blockIdx.x % 24;   // o tile
  int by = blockIdx.x / 24;   // k tile
  int tx = threadIdx.x & 31;
  int ty = threadIdx.x >> 5;  // 0..7
#pragma unroll
  for (int rr = 0; rr < 4; ++rr)
    tile[ty + rr * 8][tx] = w[(size_t)(by * 32 + ty + rr * 8) * DF + bx * 32 + tx];
  __syncthreads();
#pragma unroll
  for (int rr = 0; rr < 4; ++rr)
    wT[(size_t)(bx * 32 + ty + rr * 8) * DF + by * 32 + tx] = (f16)tile[tx][ty + rr * 8];
}

// ---------- prep: mlp_w fp32 -> f16 ----------
__global__ void prep_mlp(const float* __restrict__ mw, f16* __restrict__ mwh) {
  int i = blockIdx.x * 256 + threadIdx.x;
  mwh[i] = (f16)mw[i];
}

// ---------- fused 2-layer GAT: one workgroup (1024 thr, 16 waves) per batch item ----------
// R7: R6's 3-buffer rotation hit the scratch cliff (WRITE_SIZE 768K->78M) -> reverted
// to the R5 register footprint. New theory: R5's bfr=bnx copies forced a wait on the
// CURRENT iter's loads at iter end -> max 3 loads in flight, serialized with stall
// gaps, L2 queue repeatedly drains. Fix: explicit x2 ping-pong (Bp/Bq, NO copies).
// Wait before MFMA block is vmcnt(3), 6 loads in flight continuously, register-
// neutral vs R5 (B=24 VGPR, af[4]=16 kept). Tripwire: WRITE_SIZE > ~2MB = scratch.
__global__ __launch_bounds__(1024, 4) void gat_fused(
    const float* __restrict__ batch,
    const f16* __restrict__ wT,          // (768 x 768), wT[o][k] = w[k][o]
    const float* __restrict__ a_src,
    const float* __restrict__ a_dst,
    const float* __restrict__ gat_bias,
    f16* __restrict__ cneighW)           // (512 x 768) l2normed h[:,0]
{
  // Hbuf doubles as: h row-major (64 x LDH) and hpT (768 x LDT)
  __shared__ __align__(16) f16 Hbuf[DF * LDT];   // 110592 B
  __shared__ __align__(16) f16 attnB[NN * LDT];  // 9216 B
  __shared__ float asrcL[DF], adstL[DF], biasL[DF];
  __shared__ float srcv[NN], dstv[NN];
  __shared__ float redS[16 * NN], redD[16 * NN];
  __shared__ unsigned long long maskRow[NN];
  __shared__ float attn0[NN];
  __shared__ float h2row[DF];
  __shared__ float ssqred[16];

  const int tid  = threadIdx.x;
  const int lane = tid & 63;
  const int wv   = tid >> 6;     // wave 0..15
  const int l16  = lane & 15;
  const int quad = lane >> 4;    // 0..3
  const int b    = blockIdx.x;
  const int cb   = wv * 48;      // this wave's column base (16 waves x 48 = 768)

  const float* bb = batch + (size_t)b * (NN * DN);

  // params -> LDS
  for (int i = tid; i < DF; i += 1024) {
    asrcL[i] = a_src[i];
    adstL[i] = a_dst[i];
    biasL[i] = gat_bias[i];
  }
  // stage h0 = features (fp32 -> f16), row-major, float4-vectorized
  for (int i = tid; i < NN * (DF / 4); i += 1024) {
    int r = i / (DF / 4), c4 = i - r * (DF / 4);
    float4 v = *(const float4*)&bb[r * DN + c4 * 4];
    f16x4 h4 = {(f16)v.x, (f16)v.y, (f16)v.z, (f16)v.w};
    *(f16x4*)&Hbuf[r * LDH + c4 * 4] = h4;
  }
  // adjacency mask via ballot: wave wv builds rows 4*wv..4*wv+3
#pragma unroll
  for (int r = 0; r < 4; ++r) {
    int n = wv * 4 + r;
    float av = bb[n * DN + DF + lane];
    unsigned long long m = __ballot(av != 0.0f);
    if (lane == 0) maskRow[n] = m | (1ULL << n);   // eye
  }
  // NOTE: no barrier here — the layer-entry barrier below covers these writes,
  // and the layer-0 B preload overlaps the barrier drain.

  // per-wave wT base: columns cb+ct*16+l16, k offset quad*8
  const f16* wp = wT + (size_t)(cb + l16) * DF + quad * 8;

  for (int layer = 0; layer < 2; ++layer) {
    // ================= GEMM1: hp = h @ w =================
    f32x4 acc[4][3];
#pragma unroll
    for (int rt = 0; rt < 4; ++rt)
#pragma unroll
      for (int ct = 0; ct < 3; ++ct)
        acc[rt][ct] = (f32x4){0.f, 0.f, 0.f, 0.f};

    // ping-pong B buffers, no rotation copies
    f16x8 Bp[3], Bq[3];
#pragma unroll
    for (int ct = 0; ct < 3; ++ct)
      Bp[ct] = *(const f16x8*)(wp + (size_t)(ct * 16) * DF);
    __syncthreads();   // Hbuf (h) + params/mask ready; preload flies under drain

#pragma clang loop unroll(disable)
    for (int k0 = 0; k0 < DF; k0 += 64) {
      // ---- half A: prefetch k0+32 -> Bq, compute k0 with Bp ----
      {
        int kp = k0 + 32;   // max 736 < DF, never wraps
#pragma unroll
        for (int ct = 0; ct < 3; ++ct)
          Bq[ct] = *(const f16x8*)(wp + (size_t)(ct * 16) * DF + kp);
        f16x8 af[4];
#pragma unroll
        for (int rt = 0; rt < 4; ++rt)
          af[rt] = *(const f16x8*)&Hbuf[(rt * 16 + l16) * LDH + k0 + quad * 8];
#pragma unroll
        for (int rt = 0; rt < 4; ++rt)
#pragma unroll
          for (int ct = 0; ct < 3; ++ct)
            acc[rt][ct] = __builtin_amdgcn_mfma_f32_16x16x32_f16(af[rt], Bp[ct], acc[rt][ct], 0, 0, 0);
      }
      // ---- half B: prefetch k0+64 -> Bp, compute k0+32 with Bq ----
      {
        int kp = k0 + 64; kp = (kp < DF) ? kp : 0;   // last iter: harmless wrap
#pragma unroll
        for (int ct = 0; ct < 3; ++ct)
          Bp[ct] = *(const f16x8*)(wp + (size_t)(ct * 16) * DF + kp);
        f16x8 af[4];
#pragma unroll
        for (int rt = 0; rt < 4; ++rt)
          af[rt] = *(const f16x8*)&Hbuf[(rt * 16 + l16) * LDH + k0 + 32 + quad * 8];
#pragma unroll
        for (int rt = 0; rt < 4; ++rt)
#pragma unroll
          for (int ct = 0; ct < 3; ++ct)
            acc[rt][ct] = __builtin_amdgcn_mfma_f32_16x16x32_f16(af[rt], Bq[ct], acc[rt][ct], 0, 0, 0);
      }
    }
    __syncthreads();   // all h reads done

    // write hp transposed: hpT[o][m]; C layout row=rt*16+quad*4+i, col=cb+ct*16+l16
#pragma unroll
    for (int rt = 0; rt < 4; ++rt)
#pragma unroll
      for (int ct = 0; ct < 3; ++ct) {
        int row0 = rt * 16 + quad * 4;
        int col  = cb + ct * 16 + l16;
        f16x4 h4 = {(f16)acc[rt][ct][0], (f16)acc[rt][ct][1],
                    (f16)acc[rt][ct][2], (f16)acc[rt][ct][3]};
        *(f16x4*)&Hbuf[col * LDT + row0] = h4;
      }
    __syncthreads();

    // ================= src/dst: th = tanh(hp), dot with a_src/a_dst =================
    {
      float s = 0.f, d = 0.f;
      int m = lane;
      int o0 = wv * 48;
      for (int o = o0; o < o0 + 48; ++o) {
        float t = tanh_fast((float)Hbuf[o * LDT + m]);
        s += t * asrcL[o];
        d += t * adstL[o];
      }
      redS[wv * 64 + m] = s;
      redD[wv * 64 + m] = d;
    }
    __syncthreads();
    if (tid < 64) {
      float s = 0.f, d = 0.f;
#pragma unroll
      for (int q = 0; q < 16; ++q) { s += redS[q * 64 + tid]; d += redD[q * 64 + tid]; }
      srcv[tid] = s;
      dstv[tid] = d;
    }
    __syncthreads();

    if (layer == 0) {
      // ---- full attention: wave wv does rows 4*wv..4*wv+3, lane = neighbor m ----
#pragma unroll
      for (int r = 0; r < 4; ++r) {
        int n = wv * 4 + r;
        float logit = srcv[n] + dstv[lane];
        logit = logit >= 0.f ? logit : NEG_SLOPE * logit;
        bool ok = (maskRow[n] >> lane) & 1ULL;
        float v = ok ? logit : -1e30f;
        float mx = v;
#pragma unroll
        for (int off = 32; off > 0; off >>= 1) mx = fmaxf(mx, __shfl_xor(mx, off, 64));
        float e = ok ? __expf(v - mx) : 0.f;
        float sm = e;
#pragma unroll
        for (int off = 32; off > 0; off >>= 1) sm += __shfl_xor(sm, off, 64);
        attnB[n * LDT + lane] = (f16)(e / sm);
      }
      __syncthreads();

      // ---- GEMM2: h_new = attn @ hp  (A=attnB row-major, B=hpT) ----
      f32x4 acc2[4][3];
#pragma unroll
      for (int rt = 0; rt < 4; ++rt)
#pragma unroll
        for (int ct = 0; ct < 3; ++ct)
          acc2[rt][ct] = (f32x4){0.f, 0.f, 0.f, 0.f};
#pragma unroll
      for (int k0 = 0; k0 < NN; k0 += 32) {
        f16x8 af2[4];
#pragma unroll
        for (int rt = 0; rt < 4; ++rt)
          af2[rt] = *(const f16x8*)&attnB[(rt * 16 + l16) * LDT + k0 + quad * 8];
#pragma unroll
        for (int ct = 0; ct < 3; ++ct) {
          f16x8 bf = *(const f16x8*)&Hbuf[(cb + ct * 16 + l16) * LDT + k0 + quad * 8];
#pragma unroll
          for (int rt = 0; rt < 4; ++rt)
            acc2[rt][ct] = __builtin_amdgcn_mfma_f32_16x16x32_f16(af2[rt], bf, acc2[rt][ct], 0, 0, 0);
        }
      }
      __syncthreads();  // all hpT reads done before overwriting Hbuf
      // h_new (+bias) -> Hbuf row-major (next layer's h)
#pragma unroll
      for (int rt = 0; rt < 4; ++rt)
#pragma unroll
        for (int ct = 0; ct < 3; ++ct)
#pragma unroll
          for (int i = 0; i < 4; ++i) {
            int row = rt * 16 + quad * 4 + i;
            int col = cb + ct * 16 + l16;
            Hbuf[row * LDH + col] = (f16)(acc2[rt][ct][i] + biasL[col]);
          }
      // NOTE: no barrier here — layer-1 entry barrier (after its B preload)
      // covers these writes, overlapping the preload with the drain.
    } else {
      // ---- layer 2: only row 0 of h_new is ever used ----
      if (wv == 0) {
        float logit = srcv[0] + dstv[lane];
        logit = logit >= 0.f ? logit : NEG_SLOPE * logit;
        bool ok = (maskRow[0] >> lane) & 1ULL;
        float v = ok ? logit : -1e30f;
        float mx = v;
#pragma unroll
        for (int off = 32; off > 0; off >>= 1) mx = fmaxf(mx, __shfl_xor(mx, off, 64));
        float e = ok ? __expf(v - mx) : 0.f;
        float sm = e;
#pragma unroll
        for (int off = 32; off > 0; off >>= 1) sm += __shfl_xor(sm, off, 64);
        attn0[lane] = e / sm;   // keep fp32
      }
      __syncthreads();
      // h2_0[o] = bias[o] + sum_m attn0[m] * hpT[o][m]  (row o is 64 contiguous halves)
      if (tid < DF) {
        const int o = tid;
        const f16* rowp = &Hbuf[o * LDT];
        float a = biasL[o];
#pragma unroll
        for (int j = 0; j < 8; ++j) {
          f16x8 v = *(const f16x8*)&rowp[j * 8];
#pragma unroll
          for (int e = 0; e < 8; ++e) a += attn0[j * 8 + e] * (float)v[e];
        }
        h2row[o] = a;
      }
      __syncthreads();
      // l2norm of h2_0 -> cneighW
      float p = (tid < DF) ? h2row[tid] * h2row[tid] : 0.f;
#pragma unroll
      for (int off = 32; off > 0; off >>= 1) p += __shfl_xor(p, off, 64);
      if (lane == 0) ssqred[wv] = p;
      __syncthreads();
      if (tid == 0) {
        float ss = 0.f;
#pragma unroll
        for (int q = 0; q < 16; ++q) ss += ssqred[q];
        ssqred[0] = 1.0f / fmaxf(sqrtf(ss), 1e-12f);
      }
      __syncthreads();
      float scale = ssqred[0];
      if (tid < DF)
        cneighW[(size_t)b * DF + tid] = (f16)(h2row[tid] * scale);
    }
  }
}

// ---------- final MLP GEMM: grid (32 M-tiles, 6 N-chunks), 256 thr ----------
// 3-buffer 2-deep B pipeline (register headroom is ample at 256 thr);
// B preload hoisted above the A-stage barrier.
__global__ __launch_bounds__(256) void final_mlp(
    const float* __restrict__ batch,
    const f16* __restrict__ cneighW,
    const f16* __restrict__ mwh,         // (768 x 1536) row-major (d, j)
    const float* __restrict__ mlp_b,
    float* __restrict__ out)
{
  __shared__ __align__(16) f16 Abuf[16 * LDA];   // 49280 B
  const int tid  = threadIdx.x;
  const int lane = tid & 63;
  const int wv   = tid >> 6;          // 0..3
  const int l16  = lane & 15;
  const int quad = lane >> 4;
  const int b0   = blockIdx.x * 16;   // batch-row tile
  const int cb   = blockIdx.y * 128 + wv * 32;  // column base (2 ct of 16)

  const f16* mp = mwh + (size_t)(cb + l16) * (2 * DF) + quad * 8;
  // B preload (no LDS dep) — overlaps the A-stage + barrier
  f16x8 Ba[2], Bb[2], Bc[2];
  Ba[0] = *(const f16x8*)(mp);
  Ba[1] = *(const f16x8*)(mp + (size_t)16 * (2 * DF));
  Bb[0] = *(const f16x8*)(mp + 32);
  Bb[1] = *(const f16x8*)(mp + (size_t)16 * (2 * DF) + 32);

  // stage A: 16 rows x 1536 halves; j<768 from batch node-0 (fp32), else cneigh (f16)
  for (int i = tid; i < 16 * 384; i += 256) {
    int r = i / 384, c4 = i - r * 384;
    int j = c4 * 4;
    f16x4 h4;
    if (j < DF) {
      float4 v = *(const float4*)&batch[(size_t)(b0 + r) * (NN * DN) + j];
      h4 = (f16x4){(f16)v.x, (f16)v.y, (f16)v.z, (f16)v.w};
    } else {
      h4 = *(const f16x4*)&cneighW[(size_t)(b0 + r) * DF + (j - DF)];
    }
    *(f16x4*)&Abuf[r * LDA + j] = h4;
  }
  __syncthreads();

  f32x4 acc[2];
  acc[0] = (f32x4){0.f, 0.f, 0.f, 0.f};
  acc[1] = (f32x4){0.f, 0.f, 0.f, 0.f};

#pragma clang loop unroll(disable)
  for (int k0 = 0; k0 < 2 * DF; k0 += 96) {
    // step 0: compute k0 with Ba, prefetch k0+64 -> Bc
    {
      int kp = k0 + 64;   // max 1504 < 1536, never wraps
      Bc[0] = *(const f16x8*)(mp + kp);
      Bc[1] = *(const f16x8*)(mp + (size_t)16 * (2 * DF) + kp);
      f16x4 a0 = *(const f16x4*)&Abuf[l16 * LDA + k0 + quad * 8];
      f16x4 a1 = *(const f16x4*)&Abuf[l16 * LDA + k0 + quad * 8 + 4];
      f16x8 af = {a0[0], a0[1], a0[2], a0[3], a1[0], a1[1], a1[2], a1[3]};
      acc[0] = __builtin_amdgcn_mfma_f32_16x16x32_f16(af, Ba[0], acc[0], 0, 0, 0);
      acc[1] = __builtin_amdgcn_mfma_f32_16x16x32_f16(af, Ba[1], acc[1], 0, 0, 0);
    }
    // step 1: compute k0+32 with Bb, prefetch k0+96 -> Ba
    {
      int kp = k0 + 96; kp = (kp < 2 * DF) ? kp : 0;
      Ba[0] = *(const f16x8*)(mp + kp);
      Ba[1] = *(const f16x8*)(mp + (size_t)16 * (2 * DF) + kp);
      f16x4 a0 = *(const f16x4*)&Abuf[l16 * LDA + k0 + 32 + quad * 8];
      f16x4 a1 = *(const f16x4*)&Abuf[l16 * LDA + k0 + 32 + quad * 8 + 4];
      f16x8 af = {a0[0], a0[1], a0[2], a0[3], a1[0], a1[1], a1[2], a1[3]};
      acc[0] = __builtin_amdgcn_mfma_f32_16x16x32_f16(af, Bb[0], acc[0], 0, 0, 0);
      acc[1] = __builtin_amdgcn_mfma_f32_16x16x32_f16(af, Bb[1], acc[1], 0, 0, 0);
    }
    // step 2: compute k0+64 with Bc, prefetch k0+128 -> Bb
    {
      int kp = k0 + 128; kp = (kp < 2 * DF) ? kp : 32;
      Bb[0] = *(const f16x8*)(mp + kp);
      Bb[1] = *(const f16x8*)(mp + (size_t)16 * (2 * DF) + kp);
      f16x4 a0 = *(const f16x4*)&Abuf[l16 * LDA + k0 + 64 + quad * 8];
      f16x4 a1 = *(const f16x4*)&Abuf[l16 * LDA + k0 + 64 + quad * 8 + 4];
      f16x8 af = {a0[0], a0[1], a0[2], a0[3], a1[0], a1[1], a1[2], a1[3]};
      acc[0] = __builtin_amdgcn_mfma_f32_16x16x32_f16(af, Bc[0], acc[0], 0, 0, 0);
      acc[1] = __builtin_amdgcn_mfma_f32_16x16x32_f16(af, Bc[1], acc[1], 0, 0, 0);
    }
  }

  // epilogue: + bias, store raw (l2norm_rows normalizes)
#pragma unroll
  for (int ct = 0; ct < 2; ++ct) {
    int col = cb + ct * 16 + l16;
    float bv = mlp_b[col];
#pragma unroll
    for (int i = 0; i < 4; ++i) {
      int row = quad * 4 + i;
      out[(size_t)(b0 + row) * DF + col] = acc[ct][i] + bv;
    }
  }
}

// ---------- per-row l2 normalization of out (512 x 768 fp32) ----------
__global__ __launch_bounds__(256) void l2norm_rows(float* __restrict__ out) {
  const int lane = threadIdx.x & 63;
  const int wv   = threadIdx.x >> 6;
  const int row  = blockIdx.x * 4 + wv;
  float* rp = out + (size_t)row * DF;
  float v[12];
  float ss = 0.f;
#pragma unroll
  for (int j = 0; j < 12; ++j) {
    v[j] = rp[j * 64 + lane];
    ss += v[j] * v[j];
  }
#pragma unroll
  for (int off = 32; off > 0; off >>= 1) ss += __shfl_xor(ss, off, 64);
  float sc = 1.0f / fmaxf(sqrtf(ss), 1e-12f);
#pragma unroll
  for (int j = 0; j < 12; ++j) rp[j * 64 + lane] = v[j] * sc;
}

extern "C" void kernel_launch(void* const* d_in, const int* in_sizes, int n_in,
                              void* d_out, int out_size, void* d_ws, size_t ws_size,
                              hipStream_t stream) {
  const float* batch    = (const float*)d_in[0];  // (512, 64, 832)
  const float* w        = (const float*)d_in[1];  // (1, 768, 768)
  const float* a_src    = (const float*)d_in[2];  // (1, 768, 1)
  const float* a_dst    = (const float*)d_in[3];  // (1, 768, 1)
  const float* gat_bias = (const float*)d_in[4];  // (768,)
  const float* mlp_w    = (const float*)d_in[5];  // (768, 1536)
  const float* mlp_b    = (const float*)d_in[6];  // (768,)
  float* out = (float*)d_out;

  // workspace layout (f16): wT 768x768 | mlp_w 768x1536 | cneigh 512x768
  f16* wT      = (f16*)d_ws;
  f16* mwh     = wT + (size_t)DF * DF;
  f16* cneighW = mwh + (size_t)DF * 2 * DF;

  prep_wT<<<dim3(24 * 24), dim3(256), 0, stream>>>(w, wT);
  prep_mlp<<<dim3((DF * 2 * DF) / 256), dim3(256), 0, stream>>>(mlp_w, mwh);
  gat_fused<<<dim3(512), dim3(1024), 0, stream>>>(batch, wT, a_src, a_dst, gat_bias, cneighW);
  final_mlp<<<dim3(32, 6), dim3(256), 0, stream>>>(batch, cneighW, mwh, mlp_b, out);
  l2norm_rows<<<dim3(128), dim3(256), 0, stream>>>(out);
}

// Round 3
// 370.037 us; speedup vs baseline: 1.1129x; 1.0376x over previous
//
#include <hip/hip_runtime.h>
#include <math.h>

#define DF 768      // feature dim
#define NN 64       // nodes
#define DN 832      // batch row stride (D + N)
#define LDH 776     // h row-major LDS row stride (halves)
#define LDT 72      // hpT / attn LDS row stride (halves)
#define LDA2 388    // final_mlp A-slice row stride (halves): 194 dwords % 32 == 2, 8B-aligned
#define NEG_SLOPE 0.2f

typedef _Float16 f16;
typedef __attribute__((ext_vector_type(4))) _Float16 f16x4;
typedef __attribute__((ext_vector_type(8))) _Float16 f16x8;
typedef __attribute__((ext_vector_type(4))) float f32x4;

__device__ __forceinline__ float tanh_fast(float x) {
  return 1.0f - 2.0f / (__expf(2.0f * x) + 1.0f);
}

// ---------- prep: transpose w (768x768 fp32) -> wT[o][k] f16 ----------
__global__ void prep_wT(const float* __restrict__ w, f16* __restrict__ wT) {
  __shared__ float tile[32][33];
  int bx = blockIdx.x % 24;   // o tile
  int by = blockIdx.x / 24;   // k tile
  int tx = threadIdx.x & 31;
  int ty = threadIdx.x >> 5;  // 0..7
#pragma unroll
  for (int rr = 0; rr < 4; ++rr)
    tile[ty + rr * 8][tx] = w[(size_t)(by * 32 + ty + rr * 8) * DF + bx * 32 + tx];
  __syncthreads();
#pragma unroll
  for (int rr = 0; rr < 4; ++rr)
    wT[(size_t)(bx * 32 + ty + rr * 8) * DF + by * 32 + tx] = (f16)tile[tx][ty + rr * 8];
}

// ---------- prep: mlp_w fp32 -> f16 ----------
__global__ void prep_mlp(const float* __restrict__ mw, f16* __restrict__ mwh) {
  int i = blockIdx.x * 256 + threadIdx.x;
  mwh[i] = (f16)mw[i];
}

// ---------- fused 2-layer GAT: one workgroup (1024 thr, 16 waves) per batch item ----------
// R8: byte-for-byte revert to the R5 structure (proven 237 us, no spill).
// R6 (3-buf rotation) spilled; R7 (ping-pong) was neutral -> GEMM1 load
// latency is NOT the binding constraint; leave this kernel alone this round.
__global__ __launch_bounds__(1024, 4) void gat_fused(
    const float* __restrict__ batch,
    const f16* __restrict__ wT,          // (768 x 768), wT[o][k] = w[k][o]
    const float* __restrict__ a_src,
    const float* __restrict__ a_dst,
    const float* __restrict__ gat_bias,
    f16* __restrict__ cneighW)           // (512 x 768) l2normed h[:,0]
{
  // Hbuf doubles as: h row-major (64 x LDH) and hpT (768 x LDT)
  __shared__ __align__(16) f16 Hbuf[DF * LDT];   // 110592 B
  __shared__ __align__(16) f16 attnB[NN * LDT];  // 9216 B
  __shared__ float asrcL[DF], adstL[DF], biasL[DF];
  __shared__ float srcv[NN], dstv[NN];
  __shared__ float redS[16 * NN], redD[16 * NN];
  __shared__ unsigned long long maskRow[NN];
  __shared__ float attn0[NN];
  __shared__ float h2row[DF];
  __shared__ float ssqred[16];

  const int tid  = threadIdx.x;
  const int lane = tid & 63;
  const int wv   = tid >> 6;     // wave 0..15
  const int l16  = lane & 15;
  const int quad = lane >> 4;    // 0..3
  const int b    = blockIdx.x;
  const int cb   = wv * 48;      // this wave's column base (16 waves x 48 = 768)

  const float* bb = batch + (size_t)b * (NN * DN);

  // params -> LDS
  for (int i = tid; i < DF; i += 1024) {
    asrcL[i] = a_src[i];
    adstL[i] = a_dst[i];
    biasL[i] = gat_bias[i];
  }
  // stage h0 = features (fp32 -> f16), row-major, float4-vectorized
  for (int i = tid; i < NN * (DF / 4); i += 1024) {
    int r = i / (DF / 4), c4 = i - r * (DF / 4);
    float4 v = *(const float4*)&bb[r * DN + c4 * 4];
    f16x4 h4 = {(f16)v.x, (f16)v.y, (f16)v.z, (f16)v.w};
    *(f16x4*)&Hbuf[r * LDH + c4 * 4] = h4;
  }
  // adjacency mask via ballot: wave wv builds rows 4*wv..4*wv+3
#pragma unroll
  for (int r = 0; r < 4; ++r) {
    int n = wv * 4 + r;
    float av = bb[n * DN + DF + lane];
    unsigned long long m = __ballot(av != 0.0f);
    if (lane == 0) maskRow[n] = m | (1ULL << n);   // eye
  }
  __syncthreads();

  // per-wave wT base: columns cb+ct*16+l16, k offset quad*8
  const f16* wp = wT + (size_t)(cb + l16) * DF + quad * 8;

  for (int layer = 0; layer < 2; ++layer) {
    // ================= GEMM1: hp = h @ w =================
    f32x4 acc[4][3];
#pragma unroll
    for (int rt = 0; rt < 4; ++rt)
#pragma unroll
      for (int ct = 0; ct < 3; ++ct)
        acc[rt][ct] = (f32x4){0.f, 0.f, 0.f, 0.f};

    // software-pipelined B fragments: bfr = current, bnx = next k-step
    f16x8 bfr[3], bnx[3];
#pragma unroll
    for (int ct = 0; ct < 3; ++ct)
      bfr[ct] = *(const f16x8*)(wp + (size_t)(ct * 16) * DF);

#pragma clang loop unroll(disable)
    for (int k0 = 0; k0 < DF; k0 += 32) {
      int kn = (k0 + 32 < DF) ? (k0 + 32) : 0;   // wrap: last prefetch harmless
#pragma unroll
      for (int ct = 0; ct < 3; ++ct)
        bnx[ct] = *(const f16x8*)(wp + (size_t)(ct * 16) * DF + kn);
      f16x8 af[4];
#pragma unroll
      for (int rt = 0; rt < 4; ++rt)
        af[rt] = *(const f16x8*)&Hbuf[(rt * 16 + l16) * LDH + k0 + quad * 8];
#pragma unroll
      for (int rt = 0; rt < 4; ++rt)
#pragma unroll
        for (int ct = 0; ct < 3; ++ct)
          acc[rt][ct] = __builtin_amdgcn_mfma_f32_16x16x32_f16(af[rt], bfr[ct], acc[rt][ct], 0, 0, 0);
#pragma unroll
      for (int ct = 0; ct < 3; ++ct) bfr[ct] = bnx[ct];
    }
    __syncthreads();   // all h reads done

    // write hp transposed: hpT[o][m]; C layout row=rt*16+quad*4+i, col=cb+ct*16+l16
#pragma unroll
    for (int rt = 0; rt < 4; ++rt)
#pragma unroll
      for (int ct = 0; ct < 3; ++ct) {
        int row0 = rt * 16 + quad * 4;
        int col  = cb + ct * 16 + l16;
        f16x4 h4 = {(f16)acc[rt][ct][0], (f16)acc[rt][ct][1],
                    (f16)acc[rt][ct][2], (f16)acc[rt][ct][3]};
        *(f16x4*)&Hbuf[col * LDT + row0] = h4;
      }
    __syncthreads();

    // ================= src/dst: th = tanh(hp), dot with a_src/a_dst =================
    {
      float s = 0.f, d = 0.f;
      int m = lane;
      int o0 = wv * 48;
      for (int o = o0; o < o0 + 48; ++o) {
        float t = tanh_fast((float)Hbuf[o * LDT + m]);
        s += t * asrcL[o];
        d += t * adstL[o];
      }
      redS[wv * 64 + m] = s;
      redD[wv * 64 + m] = d;
    }
    __syncthreads();
    if (tid < 64) {
      float s = 0.f, d = 0.f;
#pragma unroll
      for (int q = 0; q < 16; ++q) { s += redS[q * 64 + tid]; d += redD[q * 64 + tid]; }
      srcv[tid] = s;
      dstv[tid] = d;
    }
    __syncthreads();

    if (layer == 0) {
      // ---- full attention: wave wv does rows 4*wv..4*wv+3, lane = neighbor m ----
#pragma unroll
      for (int r = 0; r < 4; ++r) {
        int n = wv * 4 + r;
        float logit = srcv[n] + dstv[lane];
        logit = logit >= 0.f ? logit : NEG_SLOPE * logit;
        bool ok = (maskRow[n] >> lane) & 1ULL;
        float v = ok ? logit : -1e30f;
        float mx = v;
#pragma unroll
        for (int off = 32; off > 0; off >>= 1) mx = fmaxf(mx, __shfl_xor(mx, off, 64));
        float e = ok ? __expf(v - mx) : 0.f;
        float sm = e;
#pragma unroll
        for (int off = 32; off > 0; off >>= 1) sm += __shfl_xor(sm, off, 64);
        attnB[n * LDT + lane] = (f16)(e / sm);
      }
      __syncthreads();

      // ---- GEMM2: h_new = attn @ hp  (A=attnB row-major, B=hpT) ----
      f32x4 acc2[4][3];
#pragma unroll
      for (int rt = 0; rt < 4; ++rt)
#pragma unroll
        for (int ct = 0; ct < 3; ++ct)
          acc2[rt][ct] = (f32x4){0.f, 0.f, 0.f, 0.f};
#pragma unroll
      for (int k0 = 0; k0 < NN; k0 += 32) {
        f16x8 af2[4];
#pragma unroll
        for (int rt = 0; rt < 4; ++rt)
          af2[rt] = *(const f16x8*)&attnB[(rt * 16 + l16) * LDT + k0 + quad * 8];
#pragma unroll
        for (int ct = 0; ct < 3; ++ct) {
          f16x8 bf = *(const f16x8*)&Hbuf[(cb + ct * 16 + l16) * LDT + k0 + quad * 8];
#pragma unroll
          for (int rt = 0; rt < 4; ++rt)
            acc2[rt][ct] = __builtin_amdgcn_mfma_f32_16x16x32_f16(af2[rt], bf, acc2[rt][ct], 0, 0, 0);
        }
      }
      __syncthreads();  // all hpT reads done before overwriting Hbuf
      // h_new (+bias) -> Hbuf row-major (next layer's h)
#pragma unroll
      for (int rt = 0; rt < 4; ++rt)
#pragma unroll
        for (int ct = 0; ct < 3; ++ct)
#pragma unroll
          for (int i = 0; i < 4; ++i) {
            int row = rt * 16 + quad * 4 + i;
            int col = cb + ct * 16 + l16;
            Hbuf[row * LDH + col] = (f16)(acc2[rt][ct][i] + biasL[col]);
          }
      __syncthreads();
    } else {
      // ---- layer 2: only row 0 of h_new is ever used ----
      if (wv == 0) {
        float logit = srcv[0] + dstv[lane];
        logit = logit >= 0.f ? logit : NEG_SLOPE * logit;
        bool ok = (maskRow[0] >> lane) & 1ULL;
        float v = ok ? logit : -1e30f;
        float mx = v;
#pragma unroll
        for (int off = 32; off > 0; off >>= 1) mx = fmaxf(mx, __shfl_xor(mx, off, 64));
        float e = ok ? __expf(v - mx) : 0.f;
        float sm = e;
#pragma unroll
        for (int off = 32; off > 0; off >>= 1) sm += __shfl_xor(sm, off, 64);
        attn0[lane] = e / sm;   // keep fp32
      }
      __syncthreads();
      // h2_0[o] = bias[o] + sum_m attn0[m] * hpT[o][m]  (row o is 64 contiguous halves)
      if (tid < DF) {
        const int o = tid;
        const f16* rowp = &Hbuf[o * LDT];
        float a = biasL[o];
#pragma unroll
        for (int j = 0; j < 8; ++j) {
          f16x8 v = *(const f16x8*)&rowp[j * 8];
#pragma unroll
          for (int e = 0; e < 8; ++e) a += attn0[j * 8 + e] * (float)v[e];
        }
        h2row[o] = a;
      }
      __syncthreads();
      // l2norm of h2_0 -> cneighW
      float p = (tid < DF) ? h2row[tid] * h2row[tid] : 0.f;
#pragma unroll
      for (int off = 32; off > 0; off >>= 1) p += __shfl_xor(p, off, 64);
      if (lane == 0) ssqred[wv] = p;
      __syncthreads();
      if (tid == 0) {
        float ss = 0.f;
#pragma unroll
        for (int q = 0; q < 16; ++q) ss += ssqred[q];
        ssqred[0] = 1.0f / fmaxf(sqrtf(ss), 1e-12f);
      }
      __syncthreads();
      float scale = ssqred[0];
      if (tid < DF)
        cneighW[(size_t)b * DF + tid] = (f16)(h2row[tid] * scale);
    }
  }
}

// ---------- final MLP GEMM, K split 4-way: grid (32 M-tiles, 6 N-chunks, 4 K-chunks) ----------
// R8: old grid (32,6)=192 WGs -> 1 wave/SIMD on 75% of CUs, 48-iter serial
// K-loop fully latency-exposed; hypothesis: this was ~100+ us of the fixed
// ~139 us outside gat_fused. Split K into 4 chunks of 384 -> 768 WGs
// (>=3/CU-capable, 12 KB LDS), each writes an fp32 partial; l2norm_rows
// reduces the 4 partials + bias deterministically (no atomics).
__global__ __launch_bounds__(256) void final_mlp(
    const float* __restrict__ batch,
    const f16* __restrict__ cneighW,
    const f16* __restrict__ mwh,         // (768 x 1536) row-major (d, j)
    float* __restrict__ partial)         // (4 x 512 x 768) fp32
{
  __shared__ __align__(16) f16 Abuf[16 * LDA2];   // 12416 B
  const int tid  = threadIdx.x;
  const int lane = tid & 63;
  const int wv   = tid >> 6;          // 0..3
  const int l16  = lane & 15;
  const int quad = lane >> 4;
  const int b0   = blockIdx.x * 16;   // batch-row tile
  const int cb   = blockIdx.y * 128 + wv * 32;  // column base (2 ct of 16)
  const int zc   = blockIdx.z;        // K-chunk 0..3, k in [zc*384, zc*384+384)

  const f16* mp = mwh + (size_t)(cb + l16) * (2 * DF) + zc * 384 + quad * 8;
  // B preload (no LDS dep) — overlaps the A-stage + barrier
  f16x8 bfr[2], bnx[2];
  bfr[0] = *(const f16x8*)(mp);
  bfr[1] = *(const f16x8*)(mp + (size_t)16 * (2 * DF));

  // stage A-slice: 16 rows x 384 halves; zc<2 -> from batch node-0 (fp32),
  // zc>=2 -> from cneigh (f16). 384-aligned split: branch is uniform per WG.
  for (int i = tid; i < 16 * 96; i += 256) {
    int r = i / 96, c4 = i - r * 96;
    int j = zc * 384 + c4 * 4;       // global k index
    f16x4 h4;
    if (j < DF) {
      float4 v = *(const float4*)&batch[(size_t)(b0 + r) * (NN * DN) + j];
      h4 = (f16x4){(f16)v.x, (f16)v.y, (f16)v.z, (f16)v.w};
    } else {
      h4 = *(const f16x4*)&cneighW[(size_t)(b0 + r) * DF + (j - DF)];
    }
    *(f16x4*)&Abuf[r * LDA2 + c4 * 4] = h4;
  }
  __syncthreads();

  f32x4 acc[2];
  acc[0] = (f32x4){0.f, 0.f, 0.f, 0.f};
  acc[1] = (f32x4){0.f, 0.f, 0.f, 0.f};

#pragma clang loop unroll(disable)
  for (int k0 = 0; k0 < 384; k0 += 32) {
    int kn = (k0 + 32 < 384) ? (k0 + 32) : 0;   // wrap: last prefetch harmless
    bnx[0] = *(const f16x8*)(mp + kn);
    bnx[1] = *(const f16x8*)(mp + (size_t)16 * (2 * DF) + kn);
    f16x4 a0 = *(const f16x4*)&Abuf[l16 * LDA2 + k0 + quad * 8];
    f16x4 a1 = *(const f16x4*)&Abuf[l16 * LDA2 + k0 + quad * 8 + 4];
    f16x8 af = {a0[0], a0[1], a0[2], a0[3], a1[0], a1[1], a1[2], a1[3]};
    acc[0] = __builtin_amdgcn_mfma_f32_16x16x32_f16(af, bfr[0], acc[0], 0, 0, 0);
    acc[1] = __builtin_amdgcn_mfma_f32_16x16x32_f16(af, bfr[1], acc[1], 0, 0, 0);
    bfr[0] = bnx[0];
    bfr[1] = bnx[1];
  }

  // store fp32 partial (bias added in l2norm_rows)
#pragma unroll
  for (int ct = 0; ct < 2; ++ct) {
    int col = cb + ct * 16 + l16;
#pragma unroll
    for (int i = 0; i < 4; ++i) {
      int row = quad * 4 + i;
      partial[((size_t)zc * 512 + b0 + row) * DF + col] = acc[ct][i];
    }
  }
}

// ---------- reduce 4 K-partials + bias, per-row l2 normalization ----------
__global__ __launch_bounds__(256) void l2norm_rows(
    const float* __restrict__ partial,   // (4 x 512 x 768)
    const float* __restrict__ mlp_b,
    float* __restrict__ out)             // (512 x 768)
{
  const int lane = threadIdx.x & 63;
  const int wv   = threadIdx.x >> 6;
  const int row  = blockIdx.x * 4 + wv;
  float v[12];
  float ss = 0.f;
#pragma unroll
  for (int j = 0; j < 12; ++j) {
    int col = j * 64 + lane;
    float s = partial[((size_t)0 * 512 + row) * DF + col]
            + partial[((size_t)1 * 512 + row) * DF + col]
            + partial[((size_t)2 * 512 + row) * DF + col]
            + partial[((size_t)3 * 512 + row) * DF + col]
            + mlp_b[col];
    v[j] = s;
    ss += s * s;
  }
#pragma unroll
  for (int off = 32; off > 0; off >>= 1) ss += __shfl_xor(ss, off, 64);
  float sc = 1.0f / fmaxf(sqrtf(ss), 1e-12f);
  float* rp = out + (size_t)row * DF;
#pragma unroll
  for (int j = 0; j < 12; ++j) rp[j * 64 + lane] = v[j] * sc;
}

extern "C" void kernel_launch(void* const* d_in, const int* in_sizes, int n_in,
                              void* d_out, int out_size, void* d_ws, size_t ws_size,
                              hipStream_t stream) {
  const float* batch    = (const float*)d_in[0];  // (512, 64, 832)
  const float* w        = (const float*)d_in[1];  // (1, 768, 768)
  const float* a_src    = (const float*)d_in[2];  // (1, 768, 1)
  const float* a_dst    = (const float*)d_in[3];  // (1, 768, 1)
  const float* gat_bias = (const float*)d_in[4];  // (768,)
  const float* mlp_w    = (const float*)d_in[5];  // (768, 1536)
  const float* mlp_b    = (const float*)d_in[6];  // (768,)
  float* out = (float*)d_out;

  // workspace layout: f16 wT 768x768 | f16 mlp_w 768x1536 | f16 cneigh 512x768
  //                   | fp32 partial 4x512x768
  f16* wT      = (f16*)d_ws;
  f16* mwh     = wT + (size_t)DF * DF;
  f16* cneighW = mwh + (size_t)DF * 2 * DF;
  float* partial = (float*)(cneighW + (size_t)512 * DF);  // 16B-aligned offset

  prep_wT<<<dim3(24 * 24), dim3(256), 0, stream>>>(w, wT);
  prep_mlp<<<dim3((DF * 2 * DF) / 256), dim3(256), 0, stream>>>(mlp_w, mwh);
  gat_fused<<<dim3(512), dim3(1024), 0, stream>>>(batch, wT, a_src, a_dst, gat_bias, cneighW);
  final_mlp<<<dim3(32, 6, 4), dim3(256), 0, stream>>>(batch, cneighW, mwh, partial);
  l2norm_rows<<<dim3(128), dim3(256), 0, stream>>>(partial, mlp_b, out);
}

// Round 4
// 292.542 us; speedup vs baseline: 1.4077x; 1.2649x over previous
//
#include <hip/hip_runtime.h>
#include <math.h>

#define DF 768      // feature dim
#define NN 64       // nodes
#define DN 832      // batch row stride (D + N)
#define LDH 776     // h row-major LDS row stride (halves)
#define LDT 72      // hpT / attn LDS row stride (halves)
#define LDA2 388    // final_mlp A-slice row stride (halves)
#define NEG_SLOPE 0.2f

typedef _Float16 f16;
typedef __attribute__((ext_vector_type(4))) _Float16 f16x4;
typedef __attribute__((ext_vector_type(8))) _Float16 f16x8;
typedef __attribute__((ext_vector_type(4))) float f32x4;

__device__ __forceinline__ float tanh_fast(float x) {
  return 1.0f - 2.0f / (__expf(2.0f * x) + 1.0f);
}

// ---------- prep: weights -> MFMA fragment order ----------
// R9: gat_fused's B-loads had lanes striding 1536 B -> each wave64 f16x8 load
// split into 16 cache lines (64 B used of 128 B) = 2x overfetch + 2x TA work.
// Fragment-order layout makes every B-frag load 1024 B fully contiguous:
//   wTf[((ot*24 + ks)*64 + lane)*8 + j] = w[k][o],
//     o = ot*16 + (lane&15), k = ks*32 + (lane>>4)*8 + j   (ot 0..47, ks 0..23)
//   mwf[((ot*48 + ks)*64 + lane)*8 + j] = mlp_w[o][k]      (ot 0..47, ks 0..47)
__global__ __launch_bounds__(64) void prep_frag(
    const float* __restrict__ w,    // (768 x 768), w[k][o]
    const float* __restrict__ mw,   // (768 x 1536), mlp_w[o][k]
    f16* __restrict__ wTf,
    f16* __restrict__ mwf)
{
  const int bid  = blockIdx.x;
  const int lane = threadIdx.x;   // 0..63
  const int l16  = lane & 15;
  const int quad = lane >> 4;
  if (bid < 48 * 24) {
    // wT part: bid = ot*24 + ks
    const int ot = bid / 24, ks = bid % 24;
    const int o = ot * 16 + l16;
    f16 tmp[8];
#pragma unroll
    for (int j = 0; j < 8; ++j) {
      int k = ks * 32 + quad * 8 + j;
      tmp[j] = (f16)w[(size_t)k * DF + o];
    }
    *(f16x8*)&wTf[((size_t)bid * 64 + lane) * 8] = *(f16x8*)tmp;
  } else {
    // mlp part: b2 = ot*48 + ks
    const int b2 = bid - 48 * 24;
    const int ot = b2 / 48, ks = b2 % 48;
    const int o = ot * 16 + l16;
    const float* src = &mw[(size_t)o * (2 * DF) + ks * 32 + quad * 8];
    float4 v0 = *(const float4*)src;
    float4 v1 = *(const float4*)(src + 4);
    f16x8 h = {(f16)v0.x, (f16)v0.y, (f16)v0.z, (f16)v0.w,
               (f16)v1.x, (f16)v1.y, (f16)v1.z, (f16)v1.w};
    *(f16x8*)&mwf[((size_t)b2 * 64 + lane) * 8] = h;
  }
}

// ---------- fused 2-layer GAT: one workgroup (1024 thr, 16 waves) per batch item ----------
// Structure = proven R5/R8 (237 us). Only change: B-frag loads now read the
// fragment-ordered wTf (contiguous 1024 B per wave load, ks*512-half bumps).
__global__ __launch_bounds__(1024, 4) void gat_fused(
    const float* __restrict__ batch,
    const f16* __restrict__ wTf,         // fragment-ordered w
    const float* __restrict__ a_src,
    const float* __restrict__ a_dst,
    const float* __restrict__ gat_bias,
    f16* __restrict__ cneighW)           // (512 x 768) l2normed h[:,0]
{
  // Hbuf doubles as: h row-major (64 x LDH) and hpT (768 x LDT)
  __shared__ __align__(16) f16 Hbuf[DF * LDT];   // 110592 B
  __shared__ __align__(16) f16 attnB[NN * LDT];  // 9216 B
  __shared__ float asrcL[DF], adstL[DF], biasL[DF];
  __shared__ float srcv[NN], dstv[NN];
  __shared__ float redS[16 * NN], redD[16 * NN];
  __shared__ unsigned long long maskRow[NN];
  __shared__ float attn0[NN];
  __shared__ float h2row[DF];
  __shared__ float ssqred[16];

  const int tid  = threadIdx.x;
  const int lane = tid & 63;
  const int wv   = tid >> 6;     // wave 0..15
  const int l16  = lane & 15;
  const int quad = lane >> 4;    // 0..3
  const int b    = blockIdx.x;
  const int cb   = wv * 48;      // this wave's column base (16 waves x 48 = 768)

  const float* bb = batch + (size_t)b * (NN * DN);

  // params -> LDS
  for (int i = tid; i < DF; i += 1024) {
    asrcL[i] = a_src[i];
    adstL[i] = a_dst[i];
    biasL[i] = gat_bias[i];
  }
  // stage h0 = features (fp32 -> f16), row-major, float4-vectorized
  for (int i = tid; i < NN * (DF / 4); i += 1024) {
    int r = i / (DF / 4), c4 = i - r * (DF / 4);
    float4 v = *(const float4*)&bb[r * DN + c4 * 4];
    f16x4 h4 = {(f16)v.x, (f16)v.y, (f16)v.z, (f16)v.w};
    *(f16x4*)&Hbuf[r * LDH + c4 * 4] = h4;
  }
  // adjacency mask via ballot: wave wv builds rows 4*wv..4*wv+3
#pragma unroll
  for (int r = 0; r < 4; ++r) {
    int n = wv * 4 + r;
    float av = bb[n * DN + DF + lane];
    unsigned long long m = __ballot(av != 0.0f);
    if (lane == 0) maskRow[n] = m | (1ULL << n);   // eye
  }
  __syncthreads();

  // fragment-ordered B base for this (wave, lane): ct stride 12288, ks stride 512
  const f16* wp0 = wTf + (size_t)(wv * 3) * 24 * 512 + lane * 8;

  for (int layer = 0; layer < 2; ++layer) {
    // ================= GEMM1: hp = h @ w =================
    f32x4 acc[4][3];
#pragma unroll
    for (int rt = 0; rt < 4; ++rt)
#pragma unroll
      for (int ct = 0; ct < 3; ++ct)
        acc[rt][ct] = (f32x4){0.f, 0.f, 0.f, 0.f};

    // software-pipelined B fragments: bfr = current, bnx = next k-step
    f16x8 bfr[3], bnx[3];
#pragma unroll
    for (int ct = 0; ct < 3; ++ct)
      bfr[ct] = *(const f16x8*)(wp0 + ct * 12288);

#pragma clang loop unroll(disable)
    for (int k0 = 0; k0 < DF; k0 += 32) {
      int ksn = (k0 + 32 < DF) ? ((k0 + 32) >> 5) : 0;   // wrap: harmless reload
#pragma unroll
      for (int ct = 0; ct < 3; ++ct)
        bnx[ct] = *(const f16x8*)(wp0 + ct * 12288 + ksn * 512);
      f16x8 af[4];
#pragma unroll
      for (int rt = 0; rt < 4; ++rt)
        af[rt] = *(const f16x8*)&Hbuf[(rt * 16 + l16) * LDH + k0 + quad * 8];
#pragma unroll
      for (int rt = 0; rt < 4; ++rt)
#pragma unroll
        for (int ct = 0; ct < 3; ++ct)
          acc[rt][ct] = __builtin_amdgcn_mfma_f32_16x16x32_f16(af[rt], bfr[ct], acc[rt][ct], 0, 0, 0);
#pragma unroll
      for (int ct = 0; ct < 3; ++ct) bfr[ct] = bnx[ct];
    }
    __syncthreads();   // all h reads done

    // write hp transposed: hpT[o][m]; C layout row=rt*16+quad*4+i, col=cb+ct*16+l16
#pragma unroll
    for (int rt = 0; rt < 4; ++rt)
#pragma unroll
      for (int ct = 0; ct < 3; ++ct) {
        int row0 = rt * 16 + quad * 4;
        int col  = cb + ct * 16 + l16;
        f16x4 h4 = {(f16)acc[rt][ct][0], (f16)acc[rt][ct][1],
                    (f16)acc[rt][ct][2], (f16)acc[rt][ct][3]};
        *(f16x4*)&Hbuf[col * LDT + row0] = h4;
      }
    __syncthreads();

    // ================= src/dst: th = tanh(hp), dot with a_src/a_dst =================
    {
      float s = 0.f, d = 0.f;
      int m = lane;
      int o0 = wv * 48;
      for (int o = o0; o < o0 + 48; ++o) {
        float t = tanh_fast((float)Hbuf[o * LDT + m]);
        s += t * asrcL[o];
        d += t * adstL[o];
      }
      redS[wv * 64 + m] = s;
      redD[wv * 64 + m] = d;
    }
    __syncthreads();
    if (tid < 64) {
      float s = 0.f, d = 0.f;
#pragma unroll
      for (int q = 0; q < 16; ++q) { s += redS[q * 64 + tid]; d += redD[q * 64 + tid]; }
      srcv[tid] = s;
      dstv[tid] = d;
    }
    __syncthreads();

    if (layer == 0) {
      // ---- full attention: wave wv does rows 4*wv..4*wv+3, lane = neighbor m ----
#pragma unroll
      for (int r = 0; r < 4; ++r) {
        int n = wv * 4 + r;
        float logit = srcv[n] + dstv[lane];
        logit = logit >= 0.f ? logit : NEG_SLOPE * logit;
        bool ok = (maskRow[n] >> lane) & 1ULL;
        float v = ok ? logit : -1e30f;
        float mx = v;
#pragma unroll
        for (int off = 32; off > 0; off >>= 1) mx = fmaxf(mx, __shfl_xor(mx, off, 64));
        float e = ok ? __expf(v - mx) : 0.f;
        float sm = e;
#pragma unroll
        for (int off = 32; off > 0; off >>= 1) sm += __shfl_xor(sm, off, 64);
        attnB[n * LDT + lane] = (f16)(e / sm);
      }
      __syncthreads();

      // ---- GEMM2: h_new = attn @ hp  (A=attnB row-major, B=hpT) ----
      f32x4 acc2[4][3];
#pragma unroll
      for (int rt = 0; rt < 4; ++rt)
#pragma unroll
        for (int ct = 0; ct < 3; ++ct)
          acc2[rt][ct] = (f32x4){0.f, 0.f, 0.f, 0.f};
#pragma unroll
      for (int k0 = 0; k0 < NN; k0 += 32) {
        f16x8 af2[4];
#pragma unroll
        for (int rt = 0; rt < 4; ++rt)
          af2[rt] = *(const f16x8*)&attnB[(rt * 16 + l16) * LDT + k0 + quad * 8];
#pragma unroll
        for (int ct = 0; ct < 3; ++ct) {
          f16x8 bf = *(const f16x8*)&Hbuf[(cb + ct * 16 + l16) * LDT + k0 + quad * 8];
#pragma unroll
          for (int rt = 0; rt < 4; ++rt)
            acc2[rt][ct] = __builtin_amdgcn_mfma_f32_16x16x32_f16(af2[rt], bf, acc2[rt][ct], 0, 0, 0);
        }
      }
      __syncthreads();  // all hpT reads done before overwriting Hbuf
      // h_new (+bias) -> Hbuf row-major (next layer's h)
#pragma unroll
      for (int rt = 0; rt < 4; ++rt)
#pragma unroll
        for (int ct = 0; ct < 3; ++ct)
#pragma unroll
          for (int i = 0; i < 4; ++i) {
            int row = rt * 16 + quad * 4 + i;
            int col = cb + ct * 16 + l16;
            Hbuf[row * LDH + col] = (f16)(acc2[rt][ct][i] + biasL[col]);
          }
      __syncthreads();
    } else {
      // ---- layer 2: only row 0 of h_new is ever used ----
      if (wv == 0) {
        float logit = srcv[0] + dstv[lane];
        logit = logit >= 0.f ? logit : NEG_SLOPE * logit;
        bool ok = (maskRow[0] >> lane) & 1ULL;
        float v = ok ? logit : -1e30f;
        float mx = v;
#pragma unroll
        for (int off = 32; off > 0; off >>= 1) mx = fmaxf(mx, __shfl_xor(mx, off, 64));
        float e = ok ? __expf(v - mx) : 0.f;
        float sm = e;
#pragma unroll
        for (int off = 32; off > 0; off >>= 1) sm += __shfl_xor(sm, off, 64);
        attn0[lane] = e / sm;   // keep fp32
      }
      __syncthreads();
      // h2_0[o] = bias[o] + sum_m attn0[m] * hpT[o][m]  (row o is 64 contiguous halves)
      if (tid < DF) {
        const int o = tid;
        const f16* rowp = &Hbuf[o * LDT];
        float a = biasL[o];
#pragma unroll
        for (int j = 0; j < 8; ++j) {
          f16x8 v = *(const f16x8*)&rowp[j * 8];
#pragma unroll
          for (int e = 0; e < 8; ++e) a += attn0[j * 8 + e] * (float)v[e];
        }
        h2row[o] = a;
      }
      __syncthreads();
      // l2norm of h2_0 -> cneighW
      float p = (tid < DF) ? h2row[tid] * h2row[tid] : 0.f;
#pragma unroll
      for (int off = 32; off > 0; off >>= 1) p += __shfl_xor(p, off, 64);
      if (lane == 0) ssqred[wv] = p;
      __syncthreads();
      if (tid == 0) {
        float ss = 0.f;
#pragma unroll
        for (int q = 0; q < 16; ++q) ss += ssqred[q];
        ssqred[0] = 1.0f / fmaxf(sqrtf(ss), 1e-12f);
      }
      __syncthreads();
      float scale = ssqred[0];
      if (tid < DF)
        cneighW[(size_t)b * DF + tid] = (f16)(h2row[tid] * scale);
    }
  }
}

// ---------- final MLP GEMM, K split 4-way: grid (32 M-tiles, 6 N-chunks, 4 K-chunks) ----------
// B loads now fragment-ordered (contiguous 1024 B per wave load).
__global__ __launch_bounds__(256) void final_mlp(
    const float* __restrict__ batch,
    const f16* __restrict__ cneighW,
    const f16* __restrict__ mwf,         // fragment-ordered mlp_w
    float* __restrict__ partial)         // (4 x 512 x 768) fp32
{
  __shared__ __align__(16) f16 Abuf[16 * LDA2];   // 12416 B
  const int tid  = threadIdx.x;
  const int lane = tid & 63;
  const int wv   = tid >> 6;          // 0..3
  const int l16  = lane & 15;
  const int quad = lane >> 4;
  const int b0   = blockIdx.x * 16;   // batch-row tile
  const int cb   = blockIdx.y * 128 + wv * 32;  // column base (2 ct of 16)
  const int zc   = blockIdx.z;        // K-chunk 0..3, k in [zc*384, zc*384+384)

  // fragment-ordered B base: ot = blockIdx.y*8 + wv*2 (+ct), ks = zc*12 (+k0/32)
  // ct stride = 48*512 = 24576 halves; ks stride = 512 halves
  const f16* mpf = mwf + ((size_t)(blockIdx.y * 8 + wv * 2) * 48 + zc * 12) * 512 + lane * 8;
  // B preload (no LDS dep) — overlaps the A-stage + barrier
  f16x8 bfr[2], bnx[2];
  bfr[0] = *(const f16x8*)(mpf);
  bfr[1] = *(const f16x8*)(mpf + 24576);

  // stage A-slice: 16 rows x 384 halves; zc<2 -> from batch node-0 (fp32),
  // zc>=2 -> from cneigh (f16). 384-aligned split: branch is uniform per WG.
  for (int i = tid; i < 16 * 96; i += 256) {
    int r = i / 96, c4 = i - r * 96;
    int j = zc * 384 + c4 * 4;       // global k index
    f16x4 h4;
    if (j < DF) {
      float4 v = *(const float4*)&batch[(size_t)(b0 + r) * (NN * DN) + j];
      h4 = (f16x4){(f16)v.x, (f16)v.y, (f16)v.z, (f16)v.w};
    } else {
      h4 = *(const f16x4*)&cneighW[(size_t)(b0 + r) * DF + (j - DF)];
    }
    *(f16x4*)&Abuf[r * LDA2 + c4 * 4] = h4;
  }
  __syncthreads();

  f32x4 acc[2];
  acc[0] = (f32x4){0.f, 0.f, 0.f, 0.f};
  acc[1] = (f32x4){0.f, 0.f, 0.f, 0.f};

#pragma clang loop unroll(disable)
  for (int k0 = 0; k0 < 384; k0 += 32) {
    int ksn = (k0 + 32 < 384) ? ((k0 + 32) >> 5) : 0;   // wrap: harmless reload
    bnx[0] = *(const f16x8*)(mpf + ksn * 512);
    bnx[1] = *(const f16x8*)(mpf + 24576 + ksn * 512);
    f16x4 a0 = *(const f16x4*)&Abuf[l16 * LDA2 + k0 + quad * 8];
    f16x4 a1 = *(const f16x4*)&Abuf[l16 * LDA2 + k0 + quad * 8 + 4];
    f16x8 af = {a0[0], a0[1], a0[2], a0[3], a1[0], a1[1], a1[2], a1[3]};
    acc[0] = __builtin_amdgcn_mfma_f32_16x16x32_f16(af, bfr[0], acc[0], 0, 0, 0);
    acc[1] = __builtin_amdgcn_mfma_f32_16x16x32_f16(af, bfr[1], acc[1], 0, 0, 0);
    bfr[0] = bnx[0];
    bfr[1] = bnx[1];
  }

  // store fp32 partial (bias added in l2norm_rows)
#pragma unroll
  for (int ct = 0; ct < 2; ++ct) {
    int col = cb + ct * 16 + l16;
#pragma unroll
    for (int i = 0; i < 4; ++i) {
      int row = quad * 4 + i;
      partial[((size_t)zc * 512 + b0 + row) * DF + col] = acc[ct][i];
    }
  }
}

// ---------- reduce 4 K-partials + bias, per-row l2 normalization ----------
__global__ __launch_bounds__(256) void l2norm_rows(
    const float* __restrict__ partial,   // (4 x 512 x 768)
    const float* __restrict__ mlp_b,
    float* __restrict__ out)             // (512 x 768)
{
  const int lane = threadIdx.x & 63;
  const int wv   = threadIdx.x >> 6;
  const int row  = blockIdx.x * 4 + wv;
  float v[12];
  float ss = 0.f;
#pragma unroll
  for (int j = 0; j < 12; ++j) {
    int col = j * 64 + lane;
    float s = partial[((size_t)0 * 512 + row) * DF + col]
            + partial[((size_t)1 * 512 + row) * DF + col]
            + partial[((size_t)2 * 512 + row) * DF + col]
            + partial[((size_t)3 * 512 + row) * DF + col]
            + mlp_b[col];
    v[j] = s;
    ss += s * s;
  }
#pragma unroll
  for (int off = 32; off > 0; off >>= 1) ss += __shfl_xor(ss, off, 64);
  float sc = 1.0f / fmaxf(sqrtf(ss), 1e-12f);
  float* rp = out + (size_t)row * DF;
#pragma unroll
  for (int j = 0; j < 12; ++j) rp[j * 64 + lane] = v[j] * sc;
}

extern "C" void kernel_launch(void* const* d_in, const int* in_sizes, int n_in,
                              void* d_out, int out_size, void* d_ws, size_t ws_size,
                              hipStream_t stream) {
  const float* batch    = (const float*)d_in[0];  // (512, 64, 832)
  const float* w        = (const float*)d_in[1];  // (1, 768, 768)
  const float* a_src    = (const float*)d_in[2];  // (1, 768, 1)
  const float* a_dst    = (const float*)d_in[3];  // (1, 768, 1)
  const float* gat_bias = (const float*)d_in[4];  // (768,)
  const float* mlp_w    = (const float*)d_in[5];  // (768, 1536)
  const float* mlp_b    = (const float*)d_in[6];  // (768,)
  float* out = (float*)d_out;

  // workspace layout: f16 wTf 768x768 | f16 mwf 768x1536 | f16 cneigh 512x768
  //                   | fp32 partial 4x512x768
  f16* wTf     = (f16*)d_ws;
  f16* mwf     = wTf + (size_t)DF * DF;
  f16* cneighW = mwf + (size_t)DF * 2 * DF;
  float* partial = (float*)(cneighW + (size_t)512 * DF);

  prep_frag<<<dim3(48 * 24 + 48 * 48), dim3(64), 0, stream>>>(w, mlp_w, wTf, mwf);
  gat_fused<<<dim3(512), dim3(1024), 0, stream>>>(batch, wTf, a_src, a_dst, gat_bias, cneighW);
  final_mlp<<<dim3(32, 6, 4), dim3(256), 0, stream>>>(batch, cneighW, mwf, partial);
  l2norm_rows<<<dim3(128), dim3(256), 0, stream>>>(partial, mlp_b, out);
}